// Round 9
// baseline (1255.902 us; speedup 1.0000x reference)
//
#include <hip/hip_runtime.h>
#include <math.h>

#define BB 2
#define VV 8
#define NQ 336
#define DD 256
#define HEADS 8
#define HD 32
#define FF 1024
#define NL 6
#define BQ (BB*NQ)
#define W_IMG 512
#define H_IMG 512
#define SP 384
#define MROWS BQ

// ================= job: 64x64 transpose tile =================
__device__ __forceinline__ void job_transpose(int b,
                                              const float* __restrict__ f0,
                                              const float* __restrict__ f1,
                                              const float* __restrict__ f2,
                                              float* __restrict__ o0,
                                              float* __restrict__ o1,
                                              float* __restrict__ o2) {
    const float* src; float* dst; int HW, ptiles;
    if (b < 4096)      { src = f0; dst = o0; HW = 4096; ptiles = 64; }
    else if (b < 5120) { b -= 4096; src = f1; dst = o1; HW = 1024; ptiles = 16; }
    else               { b -= 5120; src = f2; dst = o2; HW = 256;  ptiles = 4;  }
    int cg = b & 3;
    int pt = (b >> 2) % ptiles;
    int bv = (b >> 2) / ptiles;
    int d0 = cg * 64, p0 = pt * 64;
    __shared__ float tile[64][65];
    int tid = threadIdx.x;
    int t4 = tid >> 4, t15 = tid & 15;
    #pragma unroll
    for (int pass = 0; pass < 4; ++pass) {
        int d = pass * 16 + t4;
        int p = t15 * 4;
        float4 v = *(const float4*)(src + ((size_t)(bv * DD + d0 + d)) * HW + p0 + p);
        tile[d][p] = v.x; tile[d][p + 1] = v.y; tile[d][p + 2] = v.z; tile[d][p + 3] = v.w;
    }
    __syncthreads();
    #pragma unroll
    for (int pass = 0; pass < 4; ++pass) {
        int p = pass * 16 + t4;
        int d = t15 * 4;
        float4 v = make_float4(tile[d][p], tile[d + 1][p], tile[d + 2][p], tile[d + 3][p]);
        *(float4*)(dst + ((size_t)bv * HW + p0 + p) * DD + d0 + d) = v;
    }
}

// ================= transpose (5376 blocks) + init (168 blocks) =================
__global__ __launch_bounds__(256) void transpose_init(const float* __restrict__ f0,
                                                      const float* __restrict__ f1,
                                                      const float* __restrict__ f2,
                                                      float* __restrict__ o0,
                                                      float* __restrict__ o1,
                                                      float* __restrict__ o2,
                                                      const float* __restrict__ tgt,
                                                      const float* __restrict__ qp,
                                                      const float* __restrict__ refpts,
                                                      float* __restrict__ x,
                                                      float* __restrict__ xq,
                                                      float* __restrict__ refb,
                                                      int tbase) {
    int b = blockIdx.x;
    if (b < tbase) {
        job_transpose(b, f0, f1, f2, o0, o1, o2);
    } else {
        int i = (b - tbase) * 256 + threadIdx.x;
        float4 tv = ((const float4*)tgt)[i];
        float4 qv = ((const float4*)qp)[i];
        ((float4*)x)[i] = tv;
        ((float4*)xq)[i] = make_float4(tv.x + qv.x, tv.y + qv.y, tv.z + qv.z, tv.w + qv.w);
        if (i < BQ * 3) refb[i] = refpts[i];
    }
}

// ================= job: 32x64 qkv tile, head-packed output =================
__device__ __forceinline__ void job_qkv(float* sm, int bid,
                                        const float* __restrict__ Aq,
                                        const float* __restrict__ Ax,
                                        const float* __restrict__ W,
                                        const float* __restrict__ bias,
                                        float* __restrict__ Qp,
                                        float* __restrict__ Kp,
                                        float* __restrict__ Vp) {
    float* At = sm;            // [32][34]
    float* Wt = sm + 1088;     // [32][68]
    int t = threadIdx.x;
    int m0 = (bid % 21) * 32;
    int ncol = bid / 21;
    int n0 = ncol * 64;
    const float* A = (ncol < 8) ? Aq : Ax;
    int tx = t & 15, ty = t >> 4;
    int nc = n0 + tx * 4;
    float acc0[4], acc1[4];
    {
        float4 bv = *(const float4*)(bias + nc);
        acc0[0] = bv.x; acc0[1] = bv.y; acc0[2] = bv.z; acc0[3] = bv.w;
        acc1[0] = bv.x; acc1[1] = bv.y; acc1[2] = bv.z; acc1[3] = bv.w;
    }
    int am = t >> 3, ak4 = (t & 7) * 4;
    for (int kt = 0; kt < 8; ++kt) {
        int kk = kt * 32;
        __syncthreads();
        {
            float4 v = *(const float4*)(A + (size_t)(m0 + am) * DD + kk + ak4);
            At[(ak4 + 0) * 34 + am] = v.x; At[(ak4 + 1) * 34 + am] = v.y;
            At[(ak4 + 2) * 34 + am] = v.z; At[(ak4 + 3) * 34 + am] = v.w;
        }
        #pragma unroll
        for (int s = 0; s < 2; ++s) {
            int idx = t + s * 256;
            int wn = idx >> 3, wk4 = (idx & 7) * 4;
            float4 v = *(const float4*)(W + (size_t)(n0 + wn) * DD + kk + wk4);
            Wt[(wk4 + 0) * 68 + wn] = v.x; Wt[(wk4 + 1) * 68 + wn] = v.y;
            Wt[(wk4 + 2) * 68 + wn] = v.z; Wt[(wk4 + 3) * 68 + wn] = v.w;
        }
        __syncthreads();
        #pragma unroll
        for (int k = 0; k < 32; ++k) {
            float2 av = *(const float2*)&At[k * 34 + ty * 2];
            float4 wv = *(const float4*)&Wt[k * 68 + tx * 4];
            acc0[0] = fmaf(av.x, wv.x, acc0[0]); acc0[1] = fmaf(av.x, wv.y, acc0[1]);
            acc0[2] = fmaf(av.x, wv.z, acc0[2]); acc0[3] = fmaf(av.x, wv.w, acc0[3]);
            acc1[0] = fmaf(av.y, wv.x, acc1[0]); acc1[1] = fmaf(av.y, wv.y, acc1[1]);
            acc1[2] = fmaf(av.y, wv.z, acc1[2]); acc1[3] = fmaf(av.y, wv.w, acc1[3]);
        }
    }
    int mr = m0 + ty * 2;
    int kind = nc >> 8;
    float* base = kind == 0 ? Qp : (kind == 1 ? Kp : Vp);
    int h = (nc >> 5) & 7, d4 = nc & 31;
    #pragma unroll
    for (int i = 0; i < 2; ++i) {
        int m = mr + i;
        int b = m / NQ, q = m - b * NQ;
        float* p = base + ((size_t)((b << 3) + h) * NQ + q) * HD + d4;
        float* src = i == 0 ? acc0 : acc1;
        *(float4*)p = make_float4(src[0], src[1], src[2], src[3]);
    }
}

// ================= job: pose MLP + heads for 4 rows =================
__device__ __forceinline__ void job_pose(float* sm, int job,
                                         const float* __restrict__ x,
                                         const float* __restrict__ W0, const float* __restrict__ b0,
                                         const float* __restrict__ W1p, const float* __restrict__ b1p,
                                         const float* __restrict__ W2p, const float* __restrict__ b2p,
                                         const float* __restrict__ cW, const float* __restrict__ cb,
                                         float* __restrict__ refb, float* __restrict__ outp) {
    float* sX  = sm;          // 1024
    float* sH  = sm + 1024;   // 1024
    float* red = sm + 2048;   // 64
    int r0 = job * 4;
    int tid = threadIdx.x;
    ((float4*)sX)[tid] = ((const float4*)(x + (size_t)r0 * DD))[tid];
    __syncthreads();
    {
        float a0 = b0[tid], a1 = a0, a2 = a0, a3 = a0;
        const float* wp = W0 + (size_t)tid * DD;
        for (int k = 0; k < DD; k += 4) {
            float4 w  = *(const float4*)(wp + k);
            float4 x0 = *(const float4*)(sX + 0 * DD + k);
            float4 x1 = *(const float4*)(sX + 1 * DD + k);
            float4 x2 = *(const float4*)(sX + 2 * DD + k);
            float4 x3 = *(const float4*)(sX + 3 * DD + k);
            a0 = fmaf(x0.x, w.x, a0); a0 = fmaf(x0.y, w.y, a0); a0 = fmaf(x0.z, w.z, a0); a0 = fmaf(x0.w, w.w, a0);
            a1 = fmaf(x1.x, w.x, a1); a1 = fmaf(x1.y, w.y, a1); a1 = fmaf(x1.z, w.z, a1); a1 = fmaf(x1.w, w.w, a1);
            a2 = fmaf(x2.x, w.x, a2); a2 = fmaf(x2.y, w.y, a2); a2 = fmaf(x2.z, w.z, a2); a2 = fmaf(x2.w, w.w, a2);
            a3 = fmaf(x3.x, w.x, a3); a3 = fmaf(x3.y, w.y, a3); a3 = fmaf(x3.z, w.z, a3); a3 = fmaf(x3.w, w.w, a3);
        }
        sH[0 * DD + tid] = fmaxf(a0, 0.f);
        sH[1 * DD + tid] = fmaxf(a1, 0.f);
        sH[2 * DD + tid] = fmaxf(a2, 0.f);
        sH[3 * DD + tid] = fmaxf(a3, 0.f);
    }
    __syncthreads();
    float h[4];
    {
        float a0 = b1p[tid], a1 = a0, a2 = a0, a3 = a0;
        const float* wp = W1p + (size_t)tid * DD;
        for (int k = 0; k < DD; k += 4) {
            float4 w  = *(const float4*)(wp + k);
            float4 x0 = *(const float4*)(sH + 0 * DD + k);
            float4 x1 = *(const float4*)(sH + 1 * DD + k);
            float4 x2 = *(const float4*)(sH + 2 * DD + k);
            float4 x3 = *(const float4*)(sH + 3 * DD + k);
            a0 = fmaf(x0.x, w.x, a0); a0 = fmaf(x0.y, w.y, a0); a0 = fmaf(x0.z, w.z, a0); a0 = fmaf(x0.w, w.w, a0);
            a1 = fmaf(x1.x, w.x, a1); a1 = fmaf(x1.y, w.y, a1); a1 = fmaf(x1.z, w.z, a1); a1 = fmaf(x1.w, w.w, a1);
            a2 = fmaf(x2.x, w.x, a2); a2 = fmaf(x2.y, w.y, a2); a2 = fmaf(x2.z, w.z, a2); a2 = fmaf(x2.w, w.w, a2);
            a3 = fmaf(x3.x, w.x, a3); a3 = fmaf(x3.z, w.z, a3); a3 = fmaf(x3.y, w.y, a3); a3 = fmaf(x3.w, w.w, a3);
        }
        h[0] = fmaxf(a0, 0.f); h[1] = fmaxf(a1, 0.f); h[2] = fmaxf(a2, 0.f); h[3] = fmaxf(a3, 0.f);
    }
    float w2a = W2p[tid], w2b = W2p[DD + tid], w2c = W2p[2 * DD + tid], cw = cW[tid];
    float v[4][4];
    #pragma unroll
    for (int r = 0; r < 4; ++r) {
        v[r][0] = h[r] * w2a;
        v[r][1] = h[r] * w2b;
        v[r][2] = h[r] * w2c;
        v[r][3] = sX[r * DD + tid] * cw;
    }
    #pragma unroll
    for (int o2 = 32; o2 > 0; o2 >>= 1) {
        #pragma unroll
        for (int r = 0; r < 4; ++r) {
            #pragma unroll
            for (int c = 0; c < 4; ++c) v[r][c] += __shfl_xor(v[r][c], o2);
        }
    }
    int wid = tid >> 6, lane = tid & 63;
    if (lane == 0) {
        #pragma unroll
        for (int r = 0; r < 4; ++r) {
            #pragma unroll
            for (int c = 0; c < 4; ++c) red[(r * 4 + c) * 4 + wid] = v[r][c];
        }
    }
    __syncthreads();
    if (tid < 4) {
        int r = tid;
        float d0 = red[(r * 4 + 0) * 4 + 0] + red[(r * 4 + 0) * 4 + 1] + red[(r * 4 + 0) * 4 + 2] + red[(r * 4 + 0) * 4 + 3] + b2p[0];
        float d1 = red[(r * 4 + 1) * 4 + 0] + red[(r * 4 + 1) * 4 + 1] + red[(r * 4 + 1) * 4 + 2] + red[(r * 4 + 1) * 4 + 3] + b2p[1];
        float d2 = red[(r * 4 + 2) * 4 + 0] + red[(r * 4 + 2) * 4 + 1] + red[(r * 4 + 2) * 4 + 2] + red[(r * 4 + 2) * 4 + 3] + b2p[2];
        float cl = red[(r * 4 + 3) * 4 + 0] + red[(r * 4 + 3) * 4 + 1] + red[(r * 4 + 3) * 4 + 2] + red[(r * 4 + 3) * 4 + 3] + cb[0];
        int row = r0 + r;
        float rx = refb[(size_t)row * 3 + 0] + d0;
        float ry = refb[(size_t)row * 3 + 1] + d1;
        float rz = refb[(size_t)row * 3 + 2] + d2;
        refb[(size_t)row * 3 + 0] = rx;
        refb[(size_t)row * 3 + 1] = ry;
        refb[(size_t)row * 3 + 2] = rz;
        outp[(size_t)row * 4 + 0] = cl;
        outp[(size_t)row * 4 + 1] = rx;
        outp[(size_t)row * 4 + 2] = ry;
        outp[(size_t)row * 4 + 3] = rz;
    }
}

// ================= dispatch 1: qkv (252) + pose of prev layer (168) =================
__global__ __launch_bounds__(256) void qkv_pose(const float* __restrict__ xq,
                                                const float* __restrict__ x,
                                                const float* __restrict__ Wqkv,
                                                const float* __restrict__ bqkv,
                                                float* __restrict__ Qp,
                                                float* __restrict__ Kp,
                                                float* __restrict__ Vp,
                                                const float* __restrict__ pW0, const float* __restrict__ pb0,
                                                const float* __restrict__ pW1, const float* __restrict__ pb1,
                                                const float* __restrict__ pW2, const float* __restrict__ pb2,
                                                const float* __restrict__ cW, const float* __restrict__ cb,
                                                float* __restrict__ refb, float* __restrict__ outp) {
    __shared__ float sm[3264];
    if (blockIdx.x < 252)
        job_qkv(sm, blockIdx.x, xq, x, Wqkv, bqkv, Qp, Kp, Vp);
    else
        job_pose(sm, blockIdx.x - 252, x, pW0, pb0, pW1, pb1, pW2, pb2, cW, cb, refb, outp);
}

__global__ __launch_bounds__(256) void pose_only(const float* __restrict__ x,
                                                 const float* __restrict__ pW0, const float* __restrict__ pb0,
                                                 const float* __restrict__ pW1, const float* __restrict__ pb1,
                                                 const float* __restrict__ pW2, const float* __restrict__ pb2,
                                                 const float* __restrict__ cW, const float* __restrict__ cb,
                                                 float* __restrict__ refb, float* __restrict__ outp) {
    __shared__ float sm[2112];
    job_pose(sm, blockIdx.x, x, pW0, pb0, pW1, pb1, pW2, pb2, cW, cb, refb, outp);
}

// ================= job: attention scores for one (bh, qtile) =================
__device__ __forceinline__ void job_scores(float* sm, int bid,
                                           const float* __restrict__ Qp,
                                           const float* __restrict__ Kp,
                                           float* __restrict__ S) {
    int bh = bid / 6, qt = bid % 6;
    float* QT = sm;            // [32][68]
    float* KT = sm + 2176;     // [32][68]
    int t = threadIdx.x;
    const float scale = 0.17677669529663687f;
    const float* Qb = Qp + (size_t)bh * NQ * HD;
    const float* Kb = Kp + (size_t)bh * NQ * HD;
    #pragma unroll
    for (int s = 0; s < 2; ++s) {
        int idx = t + s * 256;
        int ql = idx >> 3, d4 = (idx & 7) * 4;
        int qg = qt * 64 + ql;
        float4 v = (qg < NQ) ? *(const float4*)(Qb + (size_t)qg * HD + d4)
                             : make_float4(0.f, 0.f, 0.f, 0.f);
        QT[(d4 + 0) * 68 + ql] = v.x * scale; QT[(d4 + 1) * 68 + ql] = v.y * scale;
        QT[(d4 + 2) * 68 + ql] = v.z * scale; QT[(d4 + 3) * 68 + ql] = v.w * scale;
    }
    int tx = t & 15, ty = t >> 4;
    for (int kt = 0; kt < 6; ++kt) {
        __syncthreads();
        #pragma unroll
        for (int s = 0; s < 2; ++s) {
            int idx = t + s * 256;
            int kl = idx >> 3, d4 = (idx & 7) * 4;
            int kg = kt * 64 + kl;
            float4 v = (kg < NQ) ? *(const float4*)(Kb + (size_t)kg * HD + d4)
                                 : make_float4(0.f, 0.f, 0.f, 0.f);
            KT[(d4 + 0) * 68 + kl] = v.x; KT[(d4 + 1) * 68 + kl] = v.y;
            KT[(d4 + 2) * 68 + kl] = v.z; KT[(d4 + 3) * 68 + kl] = v.w;
        }
        __syncthreads();
        float a0[4] = {0, 0, 0, 0}, a1[4] = {0, 0, 0, 0}, a2[4] = {0, 0, 0, 0}, a3[4] = {0, 0, 0, 0};
        #pragma unroll
        for (int k = 0; k < 32; ++k) {
            float4 qv = *(const float4*)&QT[k * 68 + ty * 4];
            float4 kv = *(const float4*)&KT[k * 68 + tx * 4];
            a0[0] = fmaf(qv.x, kv.x, a0[0]); a0[1] = fmaf(qv.x, kv.y, a0[1]);
            a0[2] = fmaf(qv.x, kv.z, a0[2]); a0[3] = fmaf(qv.x, kv.w, a0[3]);
            a1[0] = fmaf(qv.y, kv.x, a1[0]); a1[1] = fmaf(qv.y, kv.y, a1[1]);
            a1[2] = fmaf(qv.y, kv.z, a1[2]); a1[3] = fmaf(qv.y, kv.w, a1[3]);
            a2[0] = fmaf(qv.z, kv.x, a2[0]); a2[1] = fmaf(qv.z, kv.y, a2[1]);
            a2[2] = fmaf(qv.z, kv.z, a2[2]); a2[3] = fmaf(qv.z, kv.w, a2[3]);
            a3[0] = fmaf(qv.w, kv.x, a3[0]); a3[1] = fmaf(qv.w, kv.y, a3[1]);
            a3[2] = fmaf(qv.w, kv.z, a3[2]); a3[3] = fmaf(qv.w, kv.w, a3[3]);
        }
        int qg0 = qt * 64 + ty * 4;
        int kg0 = kt * 64 + tx * 4;
        float* Sb = S + ((size_t)bh * SP + qg0) * SP + kg0;
        *(float4*)(Sb + 0 * SP) = make_float4(a0[0], a0[1], a0[2], a0[3]);
        *(float4*)(Sb + 1 * SP) = make_float4(a1[0], a1[1], a1[2], a1[3]);
        *(float4*)(Sb + 2 * SP) = make_float4(a2[0], a2[1], a2[2], a2[3]);
        *(float4*)(Sb + 3 * SP) = make_float4(a3[0], a3[1], a3[2], a3[3]);
    }
}

// ================= job: sample one row — thread = (view, 8-channel group) =================
template <bool TRANSPOSED>
__device__ __forceinline__ void job_sample(float* sm, int row,
                                           const float* __restrict__ f0,
                                           const float* __restrict__ f1,
                                           const float* __restrict__ f2,
                                           const float* __restrict__ refb,
                                           const float* __restrict__ Rm,
                                           const float* __restrict__ Tm,
                                           const float* __restrict__ Km,
                                           float* __restrict__ fused) {
    float* sg    = sm;           // [8][3]
    float* sPart = sm + 32;      // [8][258]
    int t = threadIdx.x;
    int b = row / NQ;
    if (t < 8) {
        int bv = b * VV + t;
        const float* r = refb + (size_t)row * 3;
        const float* R = Rm + (size_t)bv * 9;
        const float* T = Tm + (size_t)bv * 3;
        const float* K = Km + (size_t)bv * 9;
        float p0 = R[0] * r[0] + R[1] * r[1] + R[2] * r[2] + T[0];
        float p1 = R[3] * r[0] + R[4] * r[1] + R[5] * r[2] + T[1];
        float p2 = R[6] * r[0] + R[7] * r[1] + R[8] * r[2] + T[2];
        float z = fmaxf(p2, 0.1f);
        float u  = p0 * K[0] / z + K[2];
        float vv = p1 * K[4] / z + K[5];
        float un = 2.f * u  / (float)(W_IMG - 1) - 1.f;
        float vn = 2.f * vv / (float)(H_IMG - 1) - 1.f;
        bool m = (un > -1.f) && (un < 1.f) && (vn > -1.f) && (vn < 1.f) && (p2 > 0.f);
        sg[t * 3 + 0] = un; sg[t * 3 + 1] = vn; sg[t * 3 + 2] = m ? 1.f : 0.f;
    }
    __syncthreads();
    int v = t >> 5, cg = t & 31;
    int ch0 = cg * 8;
    float acc[8] = {0, 0, 0, 0, 0, 0, 0, 0};
    float m = sg[v * 3 + 2];
    if (m != 0.f) {
        float un = sg[v * 3 + 0], vn = sg[v * 3 + 1];
        int bv = b * VV + v;
        const float* fl[3] = { f0, f1, f2 };
        const int Hs[3] = { 64, 32, 16 };
        #pragma unroll
        for (int lev = 0; lev < 3; ++lev) {
            int Hh = Hs[lev], Ww = Hs[lev];
            const float* f = fl[lev];
            float xx = (un + 1.f) * Ww * 0.5f - 0.5f;
            float yy = (vn + 1.f) * Hh * 0.5f - 0.5f;
            float x0f = floorf(xx), y0f = floorf(yy);
            int ix0 = (int)x0f, iy0 = (int)y0f;
            float wx1 = xx - x0f, wx0 = 1.f - wx1;
            float wy1 = yy - y0f, wy0 = 1.f - wy1;
            #pragma unroll
            for (int tap = 0; tap < 4; ++tap) {
                int ix = ix0 + (tap & 1);
                int iy = iy0 + (tap >> 1);
                float wgt = ((tap & 1) ? wx1 : wx0) * ((tap >> 1) ? wy1 : wy0);
                if (ix >= 0 && ix < Ww && iy >= 0 && iy < Hh) {
                    if (TRANSPOSED) {
                        const float* p = f + ((size_t)bv * Hh * Ww + (size_t)iy * Ww + ix) * DD + ch0;
                        float4 va = *(const float4*)p;
                        float4 vb = *(const float4*)(p + 4);
                        acc[0] = fmaf(wgt, va.x, acc[0]); acc[1] = fmaf(wgt, va.y, acc[1]);
                        acc[2] = fmaf(wgt, va.z, acc[2]); acc[3] = fmaf(wgt, va.w, acc[3]);
                        acc[4] = fmaf(wgt, vb.x, acc[4]); acc[5] = fmaf(wgt, vb.y, acc[5]);
                        acc[6] = fmaf(wgt, vb.z, acc[6]); acc[7] = fmaf(wgt, vb.w, acc[7]);
                    } else {
                        #pragma unroll
                        for (int c = 0; c < 8; ++c) {
                            float vv2 = f[(((size_t)bv * DD + ch0 + c) * Hh + iy) * Ww + ix];
                            acc[c] = fmaf(wgt, vv2, acc[c]);
                        }
                    }
                }
            }
        }
    }
    #pragma unroll
    for (int c = 0; c < 8; ++c) sPart[v * 258 + ch0 + c] = acc[c] * (1.f / 3.f);
    __syncthreads();
    float cnt = sg[2] + sg[5] + sg[8] + sg[11] + sg[14] + sg[17] + sg[20] + sg[23];
    float s = 0.f;
    #pragma unroll
    for (int v2 = 0; v2 < 8; ++v2) s += sPart[v2 * 258 + t];
    fused[(size_t)row * DD + t] = s / fmaxf(cnt, 1.f);
}

// ================= dispatch 2: scores (96) + sample (672) =================
template <bool TRANSPOSED>
__global__ __launch_bounds__(256) void scores_sample(const float* __restrict__ Qp,
                                                     const float* __restrict__ Kp,
                                                     float* __restrict__ S,
                                                     const float* __restrict__ f0,
                                                     const float* __restrict__ f1,
                                                     const float* __restrict__ f2,
                                                     const float* __restrict__ refb,
                                                     const float* __restrict__ Rm,
                                                     const float* __restrict__ Tm,
                                                     const float* __restrict__ Km,
                                                     float* __restrict__ fused) {
    __shared__ float sm[4352];
    if (blockIdx.x < 96)
        job_scores(sm, blockIdx.x, Qp, Kp, S);
    else
        job_sample<TRANSPOSED>(sm, blockIdx.x - 96, f0, f1, f2, refb, Rm, Tm, Km, fused);
}

// ================= dispatch 3: PV with fused softmax. grid (16, 6) =================
__global__ __launch_bounds__(256) void attn_pv_sm(const float* __restrict__ S,
                                                  const float* __restrict__ Vp,
                                                  float* __restrict__ O) {
    int bh = blockIdx.x, qt = blockIdx.y;
    int b = bh >> 3, h = bh & 7;
    __shared__ float Pt[64][65];
    __shared__ float Vt[64][32];
    __shared__ float smi[64][2];
    int t = threadIdx.x;
    {
        int r = t >> 2, cg = t & 3;
        const float* row = S + ((size_t)bh * SP + qt * 64 + r) * SP;
        float m = -1e30f;
        for (int i = 0; i < 84; ++i) m = fmaxf(m, row[cg + i * 4]);
        m = fmaxf(m, __shfl_xor(m, 1));
        m = fmaxf(m, __shfl_xor(m, 2));
        float ssum = 0.f;
        for (int i = 0; i < 84; ++i) ssum += expf(row[cg + i * 4] - m);
        ssum += __shfl_xor(ssum, 1);
        ssum += __shfl_xor(ssum, 2);
        if (cg == 0) { smi[r][0] = m; smi[r][1] = 1.f / ssum; }
    }
    __syncthreads();
    int tx = t & 7, ty = t >> 3;
    int d0 = tx * 4, q0 = ty * 2;
    float acc0[4] = {0, 0, 0, 0}, acc1[4] = {0, 0, 0, 0};
    for (int kt = 0; kt < 6; ++kt) {
        __syncthreads();
        #pragma unroll
        for (int s = 0; s < 4; ++s) {
            int idx = t + s * 256;
            int ql = idx >> 4, kk4 = (idx & 15) * 4;
            float4 v = *(const float4*)(S + ((size_t)bh * SP + qt * 64 + ql) * SP + kt * 64 + kk4);
            float m = smi[ql][0], inv = smi[ql][1];
            Pt[ql][kk4 + 0] = expf(v.x - m) * inv;
            Pt[ql][kk4 + 1] = expf(v.y - m) * inv;
            Pt[ql][kk4 + 2] = expf(v.z - m) * inv;
            Pt[ql][kk4 + 3] = expf(v.w - m) * inv;
        }
        #pragma unroll
        for (int s = 0; s < 2; ++s) {
            int idx = t + s * 256;
            int kl = idx >> 3, d4 = (idx & 7) * 4;
            int kg = kt * 64 + kl;
            float4 v = (kg < NQ) ? *(const float4*)(Vp + ((size_t)bh * NQ + kg) * HD + d4)
                                 : make_float4(0.f, 0.f, 0.f, 0.f);
            *(float4*)&Vt[kl][d4] = v;
        }
        __syncthreads();
        #pragma unroll 8
        for (int kk = 0; kk < 64; ++kk) {
            float4 vv = *(const float4*)&Vt[kk][d0];
            float p0 = Pt[q0][kk], p1 = Pt[q0 + 1][kk];
            acc0[0] = fmaf(p0, vv.x, acc0[0]); acc0[1] = fmaf(p0, vv.y, acc0[1]);
            acc0[2] = fmaf(p0, vv.z, acc0[2]); acc0[3] = fmaf(p0, vv.w, acc0[3]);
            acc1[0] = fmaf(p1, vv.x, acc1[0]); acc1[1] = fmaf(p1, vv.y, acc1[1]);
            acc1[2] = fmaf(p1, vv.z, acc1[2]); acc1[3] = fmaf(p1, vv.w, acc1[3]);
        }
    }
    int qg = qt * 64 + q0;
    if (qg < NQ)
        *(float4*)(O + ((size_t)(b * NQ + qg)) * DD + h * HD + d0) =
            make_float4(acc0[0], acc0[1], acc0[2], acc0[3]);
    if (qg + 1 < NQ)
        *(float4*)(O + ((size_t)(b * NQ + qg + 1)) * DD + h * HD + d0) =
            make_float4(acc1[0], acc1[1], acc1[2], acc1[3]);
}

// ================= job: row-block GEMM(K=256,N=256) + residual + LN =================
__device__ __forceinline__ void job_gemm_ln(float* sm, int r0,
                                            const float* __restrict__ A,
                                            const float* __restrict__ Wt,
                                            const float* __restrict__ bias,
                                            const float* __restrict__ gam,
                                            const float* __restrict__ bet,
                                            float* __restrict__ x) {
    float* sA    = sm;          // 1024
    float* redS  = sm + 1024;   // 16
    float* redS2 = sm + 1040;   // 16
    float* mu    = sm + 1056;   // 4
    float* ri    = sm + 1060;   // 4
    int j = threadIdx.x;
    ((float4*)sA)[j] = ((const float4*)(A + (size_t)r0 * DD))[j];
    __syncthreads();
    float acc0 = bias[j], acc1 = acc0, acc2 = acc0, acc3 = acc0;
    const float* wp = Wt + (size_t)j * DD;
    for (int k = 0; k < DD; k += 4) {
        float4 w  = *(const float4*)(wp + k);
        float4 a0 = *(const float4*)(sA + 0 * DD + k);
        float4 a1 = *(const float4*)(sA + 1 * DD + k);
        float4 a2 = *(const float4*)(sA + 2 * DD + k);
        float4 a3 = *(const float4*)(sA + 3 * DD + k);
        acc0 = fmaf(a0.x, w.x, acc0); acc0 = fmaf(a0.y, w.y, acc0); acc0 = fmaf(a0.z, w.z, acc0); acc0 = fmaf(a0.w, w.w, acc0);
        acc1 = fmaf(a1.x, w.x, acc1); acc1 = fmaf(a1.y, w.y, acc1); acc1 = fmaf(a1.z, w.z, acc1); acc1 = fmaf(a1.w, w.w, acc1);
        acc2 = fmaf(a2.x, w.x, acc2); acc2 = fmaf(a2.y, w.y, acc2); acc2 = fmaf(a2.z, w.z, acc2); acc2 = fmaf(a2.w, w.w, acc2);
        acc3 = fmaf(a3.x, w.x, acc3); acc3 = fmaf(a3.y, w.y, acc3); acc3 = fmaf(a3.z, w.z, acc3); acc3 = fmaf(a3.w, w.w, acc3);
    }
    float val[4];
    val[0] = x[(size_t)(r0 + 0) * DD + j] + acc0;
    val[1] = x[(size_t)(r0 + 1) * DD + j] + acc1;
    val[2] = x[(size_t)(r0 + 2) * DD + j] + acc2;
    val[3] = x[(size_t)(r0 + 3) * DD + j] + acc3;
    float s[4], s2[4];
    #pragma unroll
    for (int r = 0; r < 4; ++r) { s[r] = val[r]; s2[r] = val[r] * val[r]; }
    #pragma unroll
    for (int o2 = 32; o2 > 0; o2 >>= 1) {
        #pragma unroll
        for (int r = 0; r < 4; ++r) {
            s[r]  += __shfl_xor(s[r],  o2);
            s2[r] += __shfl_xor(s2[r], o2);
        }
    }
    int wid = j >> 6, lane = j & 63;
    if (lane == 0) {
        #pragma unroll
        for (int r = 0; r < 4; ++r) { redS[r * 4 + wid] = s[r]; redS2[r * 4 + wid] = s2[r]; }
    }
    __syncthreads();
    if (j < 4) {
        int r = j;
        float ts  = redS[r * 4 + 0]  + redS[r * 4 + 1]  + redS[r * 4 + 2]  + redS[r * 4 + 3];
        float ts2 = redS2[r * 4 + 0] + redS2[r * 4 + 1] + redS2[r * 4 + 2] + redS2[r * 4 + 3];
        float mean = ts * (1.f / DD);
        float var = ts2 * (1.f / DD) - mean * mean;
        mu[r] = mean;
        ri[r] = rsqrtf(var + 1e-5f);
    }
    __syncthreads();
    float g = gam[j], be = bet[j];
    #pragma unroll
    for (int r = 0; r < 4; ++r)
        x[(size_t)(r0 + r) * DD + j] = (val[r] - mu[r]) * ri[r] * g + be;
}

// ================= dispatch 4: oproj+res+LN1 then proj+res+LNpn (168 blocks) =================
__global__ __launch_bounds__(256) void oproj_proj(const float* __restrict__ attn_o,
                                                  const float* __restrict__ Wo,
                                                  const float* __restrict__ bo,
                                                  const float* __restrict__ ln1g,
                                                  const float* __restrict__ ln1b,
                                                  const float* __restrict__ fused,
                                                  const float* __restrict__ Wproj,
                                                  const float* __restrict__ bproj,
                                                  const float* __restrict__ png,
                                                  const float* __restrict__ pnb,
                                                  float* __restrict__ x) {
    __shared__ float sm[1064];
    int r0 = blockIdx.x * 4;
    job_gemm_ln(sm, r0, attn_o, Wo, bo, ln1g, ln1b, x);
    __syncthreads();
    job_gemm_ln(sm, r0, fused, Wproj, bproj, png, pnb, x);
}

// ================= dispatch 5: tiled GEMM ffn1 + relu. grid (21, 16) =================
__global__ __launch_bounds__(256) void ffn1_tile(const float* __restrict__ A,
                                                 const float* __restrict__ W,
                                                 const float* __restrict__ bias,
                                                 float* __restrict__ C) {
    __shared__ float At[32][34];
    __shared__ float Wt[32][68];
    int t = threadIdx.x;
    int m0 = blockIdx.x * 32;
    int n0 = blockIdx.y * 64;
    int tx = t & 15, ty = t >> 4;
    int nc = n0 + tx * 4;
    float acc0[4], acc1[4];
    {
        float4 bv = *(const float4*)(bias + nc);
        acc0[0] = bv.x; acc0[1] = bv.y; acc0[2] = bv.z; acc0[3] = bv.w;
        acc1[0] = bv.x; acc1[1] = bv.y; acc1[2] = bv.z; acc1[3] = bv.w;
    }
    int am = t >> 3, ak4 = (t & 7) * 4;
    for (int kt = 0; kt < 8; ++kt) {
        int kk = kt * 32;
        __syncthreads();
        {
            float4 v = *(const float4*)(A + (size_t)(m0 + am) * DD + kk + ak4);
            At[ak4 + 0][am] = v.x; At[ak4 + 1][am] = v.y;
            At[ak4 + 2][am] = v.z; At[ak4 + 3][am] = v.w;
        }
        #pragma unroll
        for (int s = 0; s < 2; ++s) {
            int idx = t + s * 256;
            int wn = idx >> 3, wk4 = (idx & 7) * 4;
            float4 v = *(const float4*)(W + (size_t)(n0 + wn) * DD + kk + wk4);
            Wt[wk4 + 0][wn] = v.x; Wt[wk4 + 1][wn] = v.y;
            Wt[wk4 + 2][wn] = v.z; Wt[wk4 + 3][wn] = v.w;
        }
        __syncthreads();
        #pragma unroll
        for (int k = 0; k < 32; ++k) {
            float2 av = *(const float2*)&At[k][ty * 2];
            float4 wv = *(const float4*)&Wt[k][tx * 4];
            acc0[0] = fmaf(av.x, wv.x, acc0[0]); acc0[1] = fmaf(av.x, wv.y, acc0[1]);
            acc0[2] = fmaf(av.x, wv.z, acc0[2]); acc0[3] = fmaf(av.x, wv.w, acc0[3]);
            acc1[0] = fmaf(av.y, wv.x, acc1[0]); acc1[1] = fmaf(av.y, wv.y, acc1[1]);
            acc1[2] = fmaf(av.y, wv.z, acc1[2]); acc1[3] = fmaf(av.y, wv.w, acc1[3]);
        }
    }
    int mr = m0 + ty * 2;
    *(float4*)(C + (size_t)mr * FF + nc) = make_float4(fmaxf(acc0[0], 0.f), fmaxf(acc0[1], 0.f),
                                                       fmaxf(acc0[2], 0.f), fmaxf(acc0[3], 0.f));
    *(float4*)(C + (size_t)(mr + 1) * FF + nc) = make_float4(fmaxf(acc1[0], 0.f), fmaxf(acc1[1], 0.f),
                                                             fmaxf(acc1[2], 0.f), fmaxf(acc1[3], 0.f));
}

// ================= dispatch 6: ffn2 (K=1024) + residual + LN2 + xq (168 blocks) =================
__global__ __launch_bounds__(256) void ffn2_ln(const float* __restrict__ ffh,
                                               const float* __restrict__ W2,
                                               const float* __restrict__ b2,
                                               const float* __restrict__ g2,
                                               const float* __restrict__ be2,
                                               const float* __restrict__ qp,
                                               float* __restrict__ x,
                                               float* __restrict__ xq) {
    __shared__ float sH[4 * FF];
    __shared__ float redS[4][4], redS2[4][4];
    __shared__ float mu[4], ri[4];
    int r0 = blockIdx.x * 4;
    int j = threadIdx.x;
    {
        const float4* src = (const float4*)(ffh + (size_t)r0 * FF);
        float4* dst = (float4*)sH;
        #pragma unroll
        for (int s = 0; s < 4; ++s) dst[j + s * 256] = src[j + s * 256];
    }
    __syncthreads();
    float acc0 = b2[j], acc1 = acc0, acc2 = acc0, acc3 = acc0;
    const float* wp = W2 + (size_t)j * FF;
    for (int k = 0; k < FF; k += 4) {
        float4 w  = *(const float4*)(wp + k);
        float4 h0 = *(const float4*)(sH + 0 * FF + k);
        float4 h1 = *(const float4*)(sH + 1 * FF + k);
        float4 h2 = *(const float4*)(sH + 2 * FF + k);
        float4 h3 = *(const float4*)(sH + 3 * FF + k);
        acc0 = fmaf(h0.x, w.x, acc0); acc0 = fmaf(h0.y, w.y, acc0); acc0 = fmaf(h0.z, w.z, acc0); acc0 = fmaf(h0.w, w.w, acc0);
        acc1 = fmaf(h1.x, w.x, acc1); acc1 = fmaf(h1.y, w.y, acc1); acc1 = fmaf(h1.z, w.z, acc1); acc1 = fmaf(h1.w, w.w, acc1);
        acc2 = fmaf(h2.x, w.x, acc2); acc2 = fmaf(h2.y, w.y, acc2); acc2 = fmaf(h2.z, w.z, acc2); acc2 = fmaf(h2.w, w.w, acc2);
        acc3 = fmaf(h3.x, w.x, acc3); acc3 = fmaf(h3.y, w.y, acc3); acc3 = fmaf(h3.z, w.z, acc3); acc3 = fmaf(h3.w, w.w, acc3);
    }
    float val[4];
    val[0] = x[(size_t)(r0 + 0) * DD + j] + acc0;
    val[1] = x[(size_t)(r0 + 1) * DD + j] + acc1;
    val[2] = x[(size_t)(r0 + 2) * DD + j] + acc2;
    val[3] = x[(size_t)(r0 + 3) * DD + j] + acc3;
    float s[4], s2[4];
    #pragma unroll
    for (int r = 0; r < 4; ++r) { s[r] = val[r]; s2[r] = val[r] * val[r]; }
    #pragma unroll
    for (int o2 = 32; o2 > 0; o2 >>= 1) {
        #pragma unroll
        for (int r = 0; r < 4; ++r) {
            s[r]  += __shfl_xor(s[r],  o2);
            s2[r] += __shfl_xor(s2[r], o2);
        }
    }
    int wid = j >> 6, lane = j & 63;
    if (lane == 0) {
        #pragma unroll
        for (int r = 0; r < 4; ++r) { redS[r][wid] = s[r]; redS2[r][wid] = s2[r]; }
    }
    __syncthreads();
    if (j < 4) {
        int r = j;
        float ts  = redS[r][0]  + redS[r][1]  + redS[r][2]  + redS[r][3];
        float ts2 = redS2[r][0] + redS2[r][1] + redS2[r][2] + redS2[r][3];
        float mean = ts * (1.f / DD);
        float var = ts2 * (1.f / DD) - mean * mean;
        mu[r] = mean;
        ri[r] = rsqrtf(var + 1e-5f);
    }
    __syncthreads();
    float g = g2[j], be = be2[j];
    #pragma unroll
    for (int r = 0; r < 4; ++r) {
        float o = (val[r] - mu[r]) * ri[r] * g + be;
        x[(size_t)(r0 + r) * DD + j]  = o;
        xq[(size_t)(r0 + r) * DD + j] = o + qp[(size_t)(r0 + r) * DD + j];
    }
}

extern "C" void kernel_launch(void* const* d_in, const int* in_sizes, int n_in,
                              void* d_out, int out_size, void* d_ws, size_t ws_size,
                              hipStream_t stream) {
    const float* tgt       = (const float*)d_in[0];
    const float* query_pos = (const float*)d_in[1];
    const float* refpts    = (const float*)d_in[2];
    const float* feat0     = (const float*)d_in[3];
    const float* feat1     = (const float*)d_in[4];
    const float* feat2     = (const float*)d_in[5];
    const float* camR      = (const float*)d_in[6];
    const float* camT      = (const float*)d_in[7];
    const float* camK      = (const float*)d_in[8];
    const float* Wqkv      = (const float*)d_in[9];
    const float* bqkv      = (const float*)d_in[10];
    const float* Wo        = (const float*)d_in[11];
    const float* bo        = (const float*)d_in[12];
    const float* ln1_g     = (const float*)d_in[13];
    const float* ln1_b     = (const float*)d_in[14];
    const float* Wproj     = (const float*)d_in[15];
    const float* bproj     = (const float*)d_in[16];
    const float* pn_g      = (const float*)d_in[17];
    const float* pn_b      = (const float*)d_in[18];
    const float* W1        = (const float*)d_in[19];
    const float* b1        = (const float*)d_in[20];
    const float* W2        = (const float*)d_in[21];
    const float* b2        = (const float*)d_in[22];
    const float* ln2_g     = (const float*)d_in[23];
    const float* ln2_b     = (const float*)d_in[24];
    const float* pose_W0   = (const float*)d_in[25];
    const float* pose_b0   = (const float*)d_in[26];
    const float* pose_W1   = (const float*)d_in[27];
    const float* pose_b1   = (const float*)d_in[28];
    const float* pose_W2   = (const float*)d_in[29];
    const float* pose_b2   = (const float*)d_in[30];
    const float* cls_W     = (const float*)d_in[31];
    const float* cls_b     = (const float*)d_in[32];
    float* out = (float*)d_out;

    float* w = (float*)d_ws;
    size_t off = 0;
    auto alloc = [&](size_t n) { float* p = w + off; off += n; return p; };
    float* x      = alloc((size_t)BQ * DD);
    float* xq     = alloc((size_t)BQ * DD);
    float* Qp     = alloc((size_t)BB * HEADS * NQ * HD);
    float* Kp     = alloc((size_t)BB * HEADS * NQ * HD);
    float* Vp     = alloc((size_t)BB * HEADS * NQ * HD);
    float* S      = alloc((size_t)BB * HEADS * SP * SP);
    float* attn_o = alloc((size_t)BQ * DD);
    float* fused  = alloc((size_t)BQ * DD);
    float* ffh    = alloc((size_t)BQ * FF);
    float* refb   = alloc((size_t)BQ * 3 + 64);
    size_t base_floats = off;
    size_t featT_floats = (size_t)BB * VV * DD * (64 * 64 + 32 * 32 + 16 * 16);
    bool useT = ws_size >= (base_floats + featT_floats) * sizeof(float);
    float *fT0 = nullptr, *fT1 = nullptr, *fT2 = nullptr;
    if (useT) {
        fT0 = alloc((size_t)BB * VV * 64 * 64 * DD);
        fT1 = alloc((size_t)BB * VV * 32 * 32 * DD);
        fT2 = alloc((size_t)BB * VV * 16 * 16 * DD);
    }

    int tbase = useT ? 5376 : 0;
    transpose_init<<<tbase + 168, 256, 0, stream>>>(feat0, feat1, feat2, fT0, fT1, fT2,
                                                    tgt, query_pos, refpts, x, xq, refb, tbase);

    for (int l = 0; l < NL; ++l) {
        // 1: qkv + pose head of layer l-1
        qkv_pose<<<252 + (l > 0 ? 168 : 0), 256, 0, stream>>>(
            xq, x, Wqkv + (size_t)l * 3 * DD * DD, bqkv + (size_t)l * 3 * DD, Qp, Kp, Vp,
            pose_W0, pose_b0, pose_W1, pose_b1, pose_W2, pose_b2, cls_W, cls_b,
            refb, out + (size_t)(l - 1) * BQ * 4);
        // 2: scores + sample (sample uses refb updated in dispatch 1)
        if (useT)
            scores_sample<true><<<96 + BQ, 256, 0, stream>>>(
                Qp, Kp, S, fT0, fT1, fT2, refb, camR, camT, camK, fused);
        else
            scores_sample<false><<<96 + BQ, 256, 0, stream>>>(
                Qp, Kp, S, feat0, feat1, feat2, refb, camR, camT, camK, fused);
        // 3: softmax + PV
        attn_pv_sm<<<dim3(BB * HEADS, 6), 256, 0, stream>>>(S, Vp, attn_o);
        // 4: oproj+res+LN1 then proj+res+LNpn
        oproj_proj<<<BQ / 4, 256, 0, stream>>>(
            attn_o, Wo + (size_t)l * DD * DD, bo + (size_t)l * DD,
            ln1_g + (size_t)l * DD, ln1_b + (size_t)l * DD,
            fused, Wproj + (size_t)l * DD * DD, bproj + (size_t)l * DD,
            pn_g + (size_t)l * DD, pn_b + (size_t)l * DD, x);
        // 5: ffn1
        ffn1_tile<<<dim3(21, 16), 256, 0, stream>>>(
            x, W1 + (size_t)l * FF * DD, b1 + (size_t)l * FF, ffh);
        // 6: ffn2 + res + LN2 + xq
        ffn2_ln<<<BQ / 4, 256, 0, stream>>>(
            ffh, W2 + (size_t)l * DD * FF, b2 + (size_t)l * DD,
            ln2_g + (size_t)l * DD, ln2_b + (size_t)l * DD, query_pos, x, xq);
    }
    pose_only<<<BQ / 4, 256, 0, stream>>>(
        x, pose_W0, pose_b0, pose_W1, pose_b1, pose_W2, pose_b2, cls_W, cls_b,
        refb, out + (size_t)(NL - 1) * BQ * 4);
}